// Round 14
// baseline (368.595 us; speedup 1.0000x reference)
//
#include <hip/hip_runtime.h>
#include <hip/hip_bf16.h>

#define T_TOK 4096
#define DDIM  1024
#define FDIM  4096
#define NEXP  8
#define TL2MAX 40  // max 256-row tiles: 8192/256 + 8 partials

typedef __attribute__((ext_vector_type(8))) short bf16x8;
typedef __attribute__((ext_vector_type(4))) float f32x4;

__device__ __forceinline__ void gl2lds16(const void* g, void* l) {
  __builtin_amdgcn_global_load_lds((const __attribute__((address_space(1))) void*)g,
                                   (__attribute__((address_space(3))) void*)l,
                                   16, 0, 0);
}

// f32 -> bf16 round-to-nearest-even (inputs finite)
__device__ __forceinline__ unsigned short f2bf(float f) {
  unsigned u = __float_as_uint(f);
  unsigned r = (u + 0x7fffu + ((u >> 16) & 1u)) >> 16;
  return (unsigned short)r;
}
__device__ __forceinline__ float bf2f(unsigned short u) {
  return __uint_as_float((unsigned)u << 16);
}

// ---------------- router: logits (f32 exact), top-2, x->bf16 (no atomics) ----------
__global__ __launch_bounds__(256) void moe_router(
    const float* __restrict__ x, const float* __restrict__ Wr,
    unsigned short* __restrict__ xb, int* __restrict__ te, float* __restrict__ tw) {
  __shared__ float wr[NEXP * DDIM];  // 32 KB
  const int tid = threadIdx.x;
#pragma unroll
  for (int i = 0; i < NEXP * DDIM / 256; ++i) wr[i * 256 + tid] = Wr[i * 256 + tid];
  __syncthreads();

  const int wave = tid >> 6, lane = tid & 63;
  const int t = blockIdx.x * 4 + wave;
  const float* xr = x + (size_t)t * DDIM;
  const int d0 = lane * 16;

  float4 xv[4];
#pragma unroll
  for (int j = 0; j < 4; ++j) xv[j] = *(const float4*)(xr + d0 + j * 4);

  float lg[NEXP];
#pragma unroll
  for (int e = 0; e < NEXP; ++e) {
    float s = 0.f;
#pragma unroll
    for (int j = 0; j < 4; ++j) {
      float4 wv = *(const float4*)(&wr[e * DDIM + d0 + j * 4]);
      s += xv[j].x * wv.x + xv[j].y * wv.y + xv[j].z * wv.z + xv[j].w * wv.w;
    }
    lg[e] = s;
  }
#pragma unroll
  for (int e = 0; e < NEXP; ++e) {
#pragma unroll
    for (int off = 32; off > 0; off >>= 1) lg[e] += __shfl_xor(lg[e], off);
  }

#pragma unroll
  for (int j = 0; j < 4; ++j) {
    ushort4 o;
    o.x = f2bf(xv[j].x); o.y = f2bf(xv[j].y); o.z = f2bf(xv[j].z); o.w = f2bf(xv[j].w);
    *(ushort4*)(xb + (size_t)t * DDIM + d0 + j * 4) = o;
  }

  if (lane == 0) {
    int i0 = 0;
#pragma unroll
    for (int e = 1; e < NEXP; ++e) if (lg[e] > lg[i0]) i0 = e;
    int i1 = (i0 == 0) ? 1 : 0;
#pragma unroll
    for (int e = 0; e < NEXP; ++e) if (e != i0 && lg[e] > lg[i1]) i1 = e;
    float w0 = 1.f / (1.f + __expf(lg[i1] - lg[i0]));
    te[t * 2 + 0] = i0; te[t * 2 + 1] = i1;
    tw[t * 2 + 0] = w0; tw[t * 2 + 1] = 1.f - w0;
  }
}

// -------- expert counts via LDS histogram (128 global atomics total) --------
__global__ __launch_bounds__(256) void moe_count(const int* __restrict__ te,
                                                 int* __restrict__ counts) {
  __shared__ int lh[NEXP];
  const int tid = threadIdx.x;
  if (tid < NEXP) lh[tid] = 0;
  __syncthreads();
  const int t = blockIdx.x * 256 + tid;
  atomicAdd(&lh[te[t * 2 + 0]], 1);
  atomicAdd(&lh[te[t * 2 + 1]], 1);
  __syncthreads();
  if (tid < NEXP) atomicAdd(&counts[tid], lh[tid]);
}

// -------- prefix over experts + build 256-row tile list --------
__global__ void moe_prefix(const int* __restrict__ counts, int* __restrict__ offs,
                           int* __restrict__ fill, int* __restrict__ tcnt,
                           int* __restrict__ tlist2) {
  if (threadIdx.x == 0) {
    int s = 0, t2 = 0;
    for (int e = 0; e < NEXP; ++e) {
      offs[e] = s;
      int c = counts[e];
      s += c;
      fill[e] = 0;
      for (int mt = 0; mt * 256 < c; ++mt) tlist2[t2++] = (e << 8) | mt;
    }
    offs[NEXP] = s;
    tcnt[1] = t2;
  }
}

// -------- scatter with LDS-aggregated ranks (128 contended global atomics) --------
__global__ __launch_bounds__(256) void moe_scatter(
    const int* __restrict__ te, const int* __restrict__ offs, int* __restrict__ fill,
    int* __restrict__ rows, int* __restrict__ slot) {
  __shared__ int lcnt[NEXP], lbase[NEXP];
  const int tid = threadIdx.x;
  if (tid < NEXP) lcnt[tid] = 0;
  __syncthreads();
  const int t = blockIdx.x * 256 + tid;
  const int e0 = te[t * 2 + 0], e1 = te[t * 2 + 1];
  const int r0 = atomicAdd(&lcnt[e0], 1);
  const int r1 = atomicAdd(&lcnt[e1], 1);
  __syncthreads();
  if (tid < NEXP) lbase[tid] = atomicAdd(&fill[tid], lcnt[tid]);
  __syncthreads();
  int p0 = offs[e0] + lbase[e0] + r0;
  int p1 = offs[e1] + lbase[e1] + r1;
  rows[p0] = t; rows[p1] = t;
  slot[t * 2 + 0] = p0; slot[t * 2 + 1] = p1;
}

// ---------------- weight convert+transpose: f32 [E][K][N] -> bf16 [E][N][K] ----------
__global__ __launch_bounds__(256) void wconv_t(const float* __restrict__ W,
                                               unsigned short* __restrict__ Wt,
                                               int K, int N) {
  __shared__ unsigned short t[64][65];
  const int e = blockIdx.z;
  const float* src = W + (size_t)e * K * N + (size_t)(blockIdx.y * 64) * N + blockIdx.x * 64;
  unsigned short* dst = Wt + (size_t)e * N * K + (size_t)(blockIdx.x * 64) * K + blockIdx.y * 64;
  const int tid = threadIdx.x;
  const int rr = tid >> 4;          // 0..15
  const int cc4 = (tid & 15) * 4;   // 0..60
#pragma unroll
  for (int i = 0; i < 4; ++i) {
    int r = i * 16 + rr;
    float4 v = *(const float4*)(src + (size_t)r * N + cc4);
    t[cc4 + 0][r] = f2bf(v.x);
    t[cc4 + 1][r] = f2bf(v.y);
    t[cc4 + 2][r] = f2bf(v.z);
    t[cc4 + 3][r] = f2bf(v.w);
  }
  __syncthreads();
  const int k8 = (tid & 7) * 8;     // 0..56
#pragma unroll
  for (int i = 0; i < 2; ++i) {
    int c = i * 32 + (tid >> 3);    // output row (n), 0..63
    uint4 pk;
    pk.x = (unsigned)t[c][k8 + 0] | ((unsigned)t[c][k8 + 1] << 16);
    pk.y = (unsigned)t[c][k8 + 2] | ((unsigned)t[c][k8 + 3] << 16);
    pk.z = (unsigned)t[c][k8 + 4] | ((unsigned)t[c][k8 + 5] << 16);
    pk.w = (unsigned)t[c][k8 + 6] | ((unsigned)t[c][k8 + 7] << 16);
    *(uint4*)(dst + (size_t)c * K + k8) = pk;
  }
}

// === grouped GEMM: 256x128 tile, BK=32, 256 thr / 4 waves (2Mx2N), per-wave 128x64 ===
// R11's proven 2-phase counted-vmcnt skeleton; geometry changed to cut ds_read/MFMA
// (12 b128 per 32 MFMA vs 8 per 16). LDS 48 KB dbuf -> 2 blocks/CU (VGPR-limited).
// 6 gl2lds/thread/step; vmcnt(6): 12 outstanding -> drains current step's 6 only.
template <int KD, int KSLICE, int ND, bool GATHER, bool DOSILU>
__global__ __launch_bounds__(256, 2) void moe_gemm(
    const unsigned short* __restrict__ Asrc, const unsigned short* __restrict__ Wt,
    const int* __restrict__ rows, const int* __restrict__ offs,
    const int* __restrict__ tcnt, const int* __restrict__ tlist2,
    unsigned short* __restrict__ Out) {
  constexpr int BM = 256, BN = 128, BK = 32;
  constexpr int S = KD / KSLICE;
  constexpr int NTN = ND / BN;
  constexpr int NPAN = NTN * S;
  constexpr int NB = TL2MAX * NPAN;        // static grid, multiple of 8

  __shared__ alignas(16) unsigned short Alds[2][BM * BK];  // 2 x 16 KB
  __shared__ alignas(16) unsigned short Blds[2][BN * BK];  // 2 x 8 KB

  // bijective XCD-chunked remap; panel-major per XCD for B-panel L2 reuse
  const int bid = blockIdx.x;
  const int orig = (bid & 7) * (NB >> 3) + (bid >> 3);
  const int TT = tcnt[1];
  if (orig >= TT * NPAN) return;
  const int tt = orig % TT;
  const int panel = orig / TT;
  const int nt = panel % NTN;
  const int ksl = panel / NTN;
  const int pk = tlist2[tt];
  const int e = pk >> 8, mt = pk & 255;

  const int base = offs[e];
  const int cnt = offs[e + 1] - base;
  const int m0 = mt * BM;
  const int valid = min(BM, cnt - m0);
  const size_t koff = (size_t)ksl * KSLICE;

  const int tid = threadIdx.x;
  const int w = tid >> 6, lane = tid & 63;
  const int wm = w >> 1, wn = w & 1;  // 2M x 2N, per-wave 128x64

  const int n0 = nt * BN;
  const unsigned short* Wb = Wt + (size_t)e * ND * KD + (size_t)n0 * KD + koff;

  // staging (measured-0-conflict swizzle family): chunk c = s*256+tid; row = c>>2;
  // phys chunk tid&3 holds logical (tid&3)^((row>>1)&3); (row>>1)&3 == (tid>>3)&3.
  const int cc8 = ((tid & 3) ^ ((tid >> 3) & 3)) * 8;
  const int ar = tid >> 2;  // 0..63; covered rows: s*64 + ar
  size_t aoff[4], boff[2];
#pragma unroll
  for (int s = 0; s < 4; ++s) {
    int r = s * 64 + ar;
    int sl = base + m0 + min(r, valid - 1);
    aoff[s] = (size_t)(GATHER ? rows[sl] : sl) * KD + koff + cc8;
  }
#pragma unroll
  for (int s = 0; s < 2; ++s) boff[s] = (size_t)(s * 64 + ar) * KD + cc8;

  // reads: row = wm*128 + mf*16 + (lane&15); chunk = (lane>>4) ^ ((row>>1)&3),
  // and (row>>1)&3 == ((lane&15)>>1)&3 (mf-independent) -> lane-only constant.
  const int rc = (lane >> 4) ^ (((lane & 15) >> 1) & 3);
  const int aro = (wm * 128 + (lane & 15)) * 64 + rc * 16;  // bytes into A buf
  const int bro = (wn * 64 + (lane & 15)) * 64 + rc * 16;   // bytes into B buf

  f32x4 acc[8][4] = {};

#define STAGE(b, k0)                                                          \
  {                                                                           \
    _Pragma("unroll") for (int s = 0; s < 4; ++s)                             \
        gl2lds16(Asrc + aoff[s] + (k0), &Alds[b][(s * 256 + tid) * 8]);       \
    _Pragma("unroll") for (int s = 0; s < 2; ++s)                             \
        gl2lds16(Wb + boff[s] + (k0), &Blds[b][(s * 256 + tid) * 8]);         \
  }

#define COMPUTE(b)                                                            \
  {                                                                           \
    bf16x8 bfr[4];                                                            \
    _Pragma("unroll") for (int nf = 0; nf < 4; ++nf)                          \
        bfr[nf] = *(const bf16x8*)((const char*)&Blds[b][0] + bro + nf * 1024); \
    {                                                                         \
      bf16x8 af[4];                                                           \
      _Pragma("unroll") for (int mf = 0; mf < 4; ++mf)                        \
          af[mf] = *(const bf16x8*)((const char*)&Alds[b][0] + aro + mf * 1024); \
      _Pragma("unroll") for (int mf = 0; mf < 4; ++mf)                        \
          _Pragma("unroll") for (int nf = 0; nf < 4; ++nf)                    \
              acc[mf][nf] = __builtin_amdgcn_mfma_f32_16x16x32_bf16(          \
                  af[mf], bfr[nf], acc[mf][nf], 0, 0, 0);                     \
    }                                                                         \
    {                                                                         \
      bf16x8 af[4];                                                           \
      _Pragma("unroll") for (int mf = 0; mf < 4; ++mf)                        \
          af[mf] = *(const bf16x8*)((const char*)&Alds[b][0] + aro + (mf + 4) * 1024); \
      _Pragma("unroll") for (int mf = 0; mf < 4; ++mf)                        \
          _Pragma("unroll") for (int nf = 0; nf < 4; ++nf)                    \
              acc[mf + 4][nf] = __builtin_amdgcn_mfma_f32_16x16x32_bf16(      \
                  af[mf], bfr[nf], acc[mf + 4][nf], 0, 0, 0);                 \
    }                                                                         \
  }

  constexpr int NK = KSLICE / BK;  // 32 or 64, always even
  STAGE(0, 0);
  for (int t = 0; t < NK; t += 2) {
    STAGE(1, (t + 1) * BK);
    asm volatile("s_waitcnt vmcnt(6)" ::: "memory");  // step t landed; t+1 in flight
    __builtin_amdgcn_s_barrier();
    COMPUTE(0);
    __builtin_amdgcn_s_barrier();
    if (t + 2 < NK) {
      STAGE(0, (t + 2) * BK);
      asm volatile("s_waitcnt vmcnt(6)" ::: "memory");
    } else {
      asm volatile("s_waitcnt vmcnt(0)" ::: "memory");
    }
    __builtin_amdgcn_s_barrier();
    COMPUTE(1);
    __builtin_amdgcn_s_barrier();
  }
#undef STAGE
#undef COMPUTE

  // epilogue: C/D layout col=lane&15, row=(lane>>4)*4+reg; bf16 store
  unsigned short* Op = Out + (size_t)ksl * 8192 * ND;
  const int q = lane >> 4, c16 = lane & 15;
#pragma unroll
  for (int mf = 0; mf < 8; ++mf) {
#pragma unroll
    for (int r = 0; r < 4; ++r) {
      int lrow = wm * 128 + mf * 16 + q * 4 + r;
      if (lrow < valid) {
#pragma unroll
        for (int nf = 0; nf < 4; ++nf) {
          int gcol = n0 + wn * 64 + nf * 16 + c16;
          float v = acc[mf][nf][r];
          if (DOSILU) v = v / (1.f + __expf(-v));
          Op[(size_t)(base + m0 + lrow) * ND + gcol] = f2bf(v);
        }
      }
    }
  }
}

// ------- final combine: out[t] = w0*(y0[s0]+y1[s0]) + w1*(y0[s1]+y1[s1]) -------
__global__ __launch_bounds__(256) void moe_combine(
    const unsigned short* __restrict__ y, const int* __restrict__ slot,
    const float* __restrict__ tw, float* __restrict__ out) {
  const int t = blockIdx.x;
  const int s0 = slot[t * 2], s1 = slot[t * 2 + 1];
  const float w0 = tw[t * 2], w1 = tw[t * 2 + 1];
  const int i = threadIdx.x * 4;
  ushort4 a = *(const ushort4*)(y + (size_t)s0 * DDIM + i);
  ushort4 b = *(const ushort4*)(y + (size_t)(8192 + s0) * DDIM + i);
  ushort4 c = *(const ushort4*)(y + (size_t)s1 * DDIM + i);
  ushort4 d = *(const ushort4*)(y + (size_t)(8192 + s1) * DDIM + i);
  float4 r;
  r.x = w0 * (bf2f(a.x) + bf2f(b.x)) + w1 * (bf2f(c.x) + bf2f(d.x));
  r.y = w0 * (bf2f(a.y) + bf2f(b.y)) + w1 * (bf2f(c.y) + bf2f(d.y));
  r.z = w0 * (bf2f(a.z) + bf2f(b.z)) + w1 * (bf2f(c.z) + bf2f(d.z));
  r.w = w0 * (bf2f(a.w) + bf2f(b.w)) + w1 * (bf2f(c.w) + bf2f(d.w));
  *(float4*)(out + (size_t)t * DDIM + i) = r;
}

extern "C" void kernel_launch(void* const* d_in, const int* in_sizes, int n_in,
                              void* d_out, int out_size, void* d_ws, size_t ws_size,
                              hipStream_t stream) {
  const float* x  = (const float*)d_in[0];   // [2,2048,1024]
  const float* Wr = (const float*)d_in[1];   // [8,1024]
  const float* W1 = (const float*)d_in[2];   // [8,1024,4096]
  const float* W2 = (const float*)d_in[3];   // [8,4096,1024]
  float* out = (float*)d_out;                // [2,2048,1024] f32

  char* ws = (char*)d_ws;
  unsigned short* xb = (unsigned short*)ws;                          // 8 MB bf16 tokens
  unsigned short* H  = (unsigned short*)(ws + (size_t)(8 << 20));    // 64 MB bf16 hidden
  unsigned short* WT = (unsigned short*)(ws + (size_t)(72 << 20));   // 64 MB bf16 Wt (shared)
  unsigned short* y  = (unsigned short*)(ws + (size_t)(136 << 20));  // 32 MB bf16 y-pair
  char* meta = ws + (size_t)(168 << 20);
  int* rows   = (int*)meta;                   // 32 KB
  int* te     = (int*)(meta + (32 << 10));    // 32 KB
  float* tw   = (float*)(meta + (64 << 10));  // 32 KB
  int* slot   = (int*)(meta + (96 << 10));    // 32 KB
  int* counts = (int*)(meta + (128 << 10));
  int* offs   = counts + 16;
  int* fill   = counts + 32;
  int* tcnt   = counts + 48;
  int* tlist2 = counts + 64;                  // <= 40 entries

  hipMemsetAsync(counts, 0, 1024, stream);

  moe_router<<<T_TOK / 4, 256, 0, stream>>>(x, Wr, xb, te, tw);
  moe_count<<<T_TOK / 256, 256, 0, stream>>>(te, counts);
  moe_prefix<<<1, 64, 0, stream>>>(counts, offs, fill, tcnt, tlist2);
  moe_scatter<<<T_TOK / 256, 256, 0, stream>>>(te, offs, fill, rows, slot);

  // W1 [E][D=1024][F=4096] -> WT [E][F][D]
  wconv_t<<<dim3(FDIM / 64, DDIM / 64, NEXP), 256, 0, stream>>>(W1, WT, DDIM, FDIM);
  // GEMM1: H[slot] = silu(x[rows[slot]] @ W1[e]); 256x128 tiles, 128x64 waves
  moe_gemm<DDIM, DDIM, FDIM, true, true>
      <<<TL2MAX * (FDIM / 128), 256, 0, stream>>>(xb, WT, rows, offs, tcnt, tlist2, H);

  // W2 [E][F=4096][D=1024] -> WT [E][D][F]
  wconv_t<<<dim3(DDIM / 64, FDIM / 64, NEXP), 256, 0, stream>>>(W2, WT, FDIM, DDIM);
  // GEMM2: split-K=2 -> bf16 partial pair y[2][8192][1024]
  moe_gemm<FDIM, FDIM / 2, DDIM, false, false>
      <<<TL2MAX * (DDIM / 128) * 2, 256, 0, stream>>>(H, WT, nullptr, offs, tcnt, tlist2, y);

  moe_combine<<<T_TOK, 256, 0, stream>>>(y, slot, tw, out);
}

// Round 15
// 311.137 us; speedup vs baseline: 1.1847x; 1.1847x over previous
//
#include <hip/hip_runtime.h>
#include <hip/hip_bf16.h>

#define T_TOK 4096
#define DDIM  1024
#define FDIM  4096
#define NEXP  8
#define TLMAX 136  // max 64-row tiles: 8192/64 + 8 partials

typedef __attribute__((ext_vector_type(8))) short bf16x8;
typedef __attribute__((ext_vector_type(4))) float f32x4;

__device__ __forceinline__ void gl2lds16(const void* g, void* l) {
  __builtin_amdgcn_global_load_lds((const __attribute__((address_space(1))) void*)g,
                                   (__attribute__((address_space(3))) void*)l,
                                   16, 0, 0);
}

// f32 -> bf16 round-to-nearest-even (inputs finite)
__device__ __forceinline__ unsigned short f2bf(float f) {
  unsigned u = __float_as_uint(f);
  unsigned r = (u + 0x7fffu + ((u >> 16) & 1u)) >> 16;
  return (unsigned short)r;
}
__device__ __forceinline__ float bf2f(unsigned short u) {
  return __uint_as_float((unsigned)u << 16);
}

// ---------------- router: logits (f32 exact), top-2, x->bf16 (no atomics) ----------
__global__ __launch_bounds__(256) void moe_router(
    const float* __restrict__ x, const float* __restrict__ Wr,
    unsigned short* __restrict__ xb, int* __restrict__ te, float* __restrict__ tw) {
  __shared__ float wr[NEXP * DDIM];  // 32 KB
  const int tid = threadIdx.x;
#pragma unroll
  for (int i = 0; i < NEXP * DDIM / 256; ++i) wr[i * 256 + tid] = Wr[i * 256 + tid];
  __syncthreads();

  const int wave = tid >> 6, lane = tid & 63;
  const int t = blockIdx.x * 4 + wave;
  const float* xr = x + (size_t)t * DDIM;
  const int d0 = lane * 16;

  float4 xv[4];
#pragma unroll
  for (int j = 0; j < 4; ++j) xv[j] = *(const float4*)(xr + d0 + j * 4);

  float lg[NEXP];
#pragma unroll
  for (int e = 0; e < NEXP; ++e) {
    float s = 0.f;
#pragma unroll
    for (int j = 0; j < 4; ++j) {
      float4 wv = *(const float4*)(&wr[e * DDIM + d0 + j * 4]);
      s += xv[j].x * wv.x + xv[j].y * wv.y + xv[j].z * wv.z + xv[j].w * wv.w;
    }
    lg[e] = s;
  }
#pragma unroll
  for (int e = 0; e < NEXP; ++e) {
#pragma unroll
    for (int off = 32; off > 0; off >>= 1) lg[e] += __shfl_xor(lg[e], off);
  }

#pragma unroll
  for (int j = 0; j < 4; ++j) {
    ushort4 o;
    o.x = f2bf(xv[j].x); o.y = f2bf(xv[j].y); o.z = f2bf(xv[j].z); o.w = f2bf(xv[j].w);
    *(ushort4*)(xb + (size_t)t * DDIM + d0 + j * 4) = o;
  }

  if (lane == 0) {
    int i0 = 0;
#pragma unroll
    for (int e = 1; e < NEXP; ++e) if (lg[e] > lg[i0]) i0 = e;
    int i1 = (i0 == 0) ? 1 : 0;
#pragma unroll
    for (int e = 0; e < NEXP; ++e) if (e != i0 && lg[e] > lg[i1]) i1 = e;
    float w0 = 1.f / (1.f + __expf(lg[i1] - lg[i0]));
    te[t * 2 + 0] = i0; te[t * 2 + 1] = i1;
    tw[t * 2 + 0] = w0; tw[t * 2 + 1] = 1.f - w0;
  }
}

// -------- expert counts via LDS histogram (128 global atomics total) --------
__global__ __launch_bounds__(256) void moe_count(const int* __restrict__ te,
                                                 int* __restrict__ counts) {
  __shared__ int lh[NEXP];
  const int tid = threadIdx.x;
  if (tid < NEXP) lh[tid] = 0;
  __syncthreads();
  const int t = blockIdx.x * 256 + tid;
  atomicAdd(&lh[te[t * 2 + 0]], 1);
  atomicAdd(&lh[te[t * 2 + 1]], 1);
  __syncthreads();
  if (tid < NEXP) atomicAdd(&counts[tid], lh[tid]);
}

// -------- prefix over experts + build balanced 64-row tile list --------
__global__ void moe_prefix(const int* __restrict__ counts, int* __restrict__ offs,
                           int* __restrict__ fill, int* __restrict__ tcnt,
                           int* __restrict__ tlist) {
  if (threadIdx.x == 0) {
    int s = 0, tt = 0;
    for (int e = 0; e < NEXP; ++e) {
      offs[e] = s;
      int c = counts[e];
      s += c;
      fill[e] = 0;
      for (int mt = 0; mt * 64 < c; ++mt) tlist[tt++] = (e << 8) | mt;
    }
    offs[NEXP] = s;
    tcnt[0] = tt;
  }
}

// -------- scatter with LDS-aggregated ranks (128 contended global atomics) --------
__global__ __launch_bounds__(256) void moe_scatter(
    const int* __restrict__ te, const int* __restrict__ offs, int* __restrict__ fill,
    int* __restrict__ rows, int* __restrict__ slot) {
  __shared__ int lcnt[NEXP], lbase[NEXP];
  const int tid = threadIdx.x;
  if (tid < NEXP) lcnt[tid] = 0;
  __syncthreads();
  const int t = blockIdx.x * 256 + tid;
  const int e0 = te[t * 2 + 0], e1 = te[t * 2 + 1];
  const int r0 = atomicAdd(&lcnt[e0], 1);
  const int r1 = atomicAdd(&lcnt[e1], 1);
  __syncthreads();
  if (tid < NEXP) lbase[tid] = atomicAdd(&fill[tid], lcnt[tid]);
  __syncthreads();
  int p0 = offs[e0] + lbase[e0] + r0;
  int p1 = offs[e1] + lbase[e1] + r1;
  rows[p0] = t; rows[p1] = t;
  slot[t * 2 + 0] = p0; slot[t * 2 + 1] = p1;
}

// ---------------- weight convert+transpose: f32 [E][K][N] -> bf16 [E][N][K] ----------
__global__ __launch_bounds__(256) void wconv_t(const float* __restrict__ W,
                                               unsigned short* __restrict__ Wt,
                                               int K, int N) {
  __shared__ unsigned short t[64][65];
  const int e = blockIdx.z;
  const float* src = W + (size_t)e * K * N + (size_t)(blockIdx.y * 64) * N + blockIdx.x * 64;
  unsigned short* dst = Wt + (size_t)e * N * K + (size_t)(blockIdx.x * 64) * K + blockIdx.y * 64;
  const int tid = threadIdx.x;
  const int rr = tid >> 4;          // 0..15
  const int cc4 = (tid & 15) * 4;   // 0..60
#pragma unroll
  for (int i = 0; i < 4; ++i) {
    int r = i * 16 + rr;
    float4 v = *(const float4*)(src + (size_t)r * N + cc4);
    t[cc4 + 0][r] = f2bf(v.x);
    t[cc4 + 1][r] = f2bf(v.y);
    t[cc4 + 2][r] = f2bf(v.z);
    t[cc4 + 3][r] = f2bf(v.w);
  }
  __syncthreads();
  const int k8 = (tid & 7) * 8;     // 0..56
#pragma unroll
  for (int i = 0; i < 2; ++i) {
    int c = i * 32 + (tid >> 3);    // output row (n), 0..63
    uint4 pk;
    pk.x = (unsigned)t[c][k8 + 0] | ((unsigned)t[c][k8 + 1] << 16);
    pk.y = (unsigned)t[c][k8 + 2] | ((unsigned)t[c][k8 + 3] << 16);
    pk.z = (unsigned)t[c][k8 + 4] | ((unsigned)t[c][k8 + 5] << 16);
    pk.w = (unsigned)t[c][k8 + 6] | ((unsigned)t[c][k8 + 7] << 16);
    *(uint4*)(dst + (size_t)c * K + k8) = pk;
  }
}

// ------- grouped GEMM: 64x256 tile, BK=64, 8 waves (2Mx4N), 2-phase counted dbuf ----
// Optional split-K (KSLICE < KD): slice ksl writes bf16 partials at Out+ksl*8192*ND.
// Output always bf16; DOSILU applies silu before store.
template <int KD, int KSLICE, int ND, bool GATHER, bool DOSILU>
__global__ __launch_bounds__(512, 4) void moe_gemm(
    const unsigned short* __restrict__ Asrc, const unsigned short* __restrict__ Wt,
    const int* __restrict__ rows, const int* __restrict__ offs,
    const int* __restrict__ tcnt, const int* __restrict__ tlist,
    unsigned short* __restrict__ Out) {
  constexpr int BM = 64, BN = 256;
  constexpr int S = KD / KSLICE;
  constexpr int NTN = ND / BN;
  constexpr int NPAN = NTN * S;
  constexpr int NB = TLMAX * NPAN;         // static grid, multiple of 8
  constexpr int CB = BN / 64;
  constexpr int MF = BM / 32, NF = 4;

  __shared__ alignas(16) unsigned short Alds[2][BM * 64];  // 2 x 8 KB
  __shared__ alignas(16) unsigned short Blds[2][BN * 64];  // 2 x 32 KB

  // bijective XCD-chunked remap over static NB; tt fastest -> panels chunked per XCD
  const int bid = blockIdx.x;
  const int orig = (bid & 7) * (NB >> 3) + (bid >> 3);
  const int TT = tcnt[0];
  if (orig >= TT * NPAN) return;
  const int tt = orig % TT;
  const int panel = orig / TT;
  const int nt = panel % NTN;
  const int ksl = panel / NTN;
  const int pk = tlist[tt];
  const int e = pk >> 8, mt = pk & 255;

  const int base = offs[e];
  const int cnt = offs[e + 1] - base;
  const int m0 = mt * BM;
  const int valid = min(BM, cnt - m0);
  const size_t koff = (size_t)ksl * KSLICE;

  const int tid = threadIdx.x;
  const int w = tid >> 6, lane = tid & 63;
  const int wm = w >> 2, wn = w & 3;

  const int n0 = nt * BN;
  const unsigned short* Wb = Wt + (size_t)e * ND * KD + (size_t)n0 * KD + koff;

  // staging addresses; A: one row per thread (row = w*8 + lane>>3), swizzled 16B chunk
  const int cc8 = ((lane & 7) ^ (lane >> 3)) * 8;
  const int ar = w * 8 + (lane >> 3);
  const int aslot = base + m0 + min(ar, valid - 1);
  const size_t aoff = (size_t)(GATHER ? rows[aslot] : aslot) * KD + koff + cc8;
  size_t boff[CB];
#pragma unroll
  for (int s = 0; s < CB; ++s) {
    int r = s * 64 + w * 8 + (lane >> 3);
    boff[s] = (size_t)r * KD + cc8;
  }

  f32x4 acc[MF][NF] = {};

#define STAGE(b, k0)                                                         \
  {                                                                          \
    gl2lds16(Asrc + aoff + (k0), &Alds[b][w * 512]);                         \
    _Pragma("unroll") for (int s = 0; s < CB; ++s)                           \
        gl2lds16(Wb + boff[s] + (k0), &Blds[b][(s * 512 + w * 64) * 8]);     \
  }

#define COMPUTE(b)                                                           \
  {                                                                          \
    _Pragma("unroll") for (int ks = 0; ks < 2; ++ks) {                       \
      bf16x8 af[MF], bfr[NF];                                                \
      _Pragma("unroll") for (int mf = 0; mf < MF; ++mf) {                    \
        int row = wm * 32 + mf * 16 + (lane & 15);                           \
        int cc = ks * 4 + (lane >> 4);                                       \
        af[mf] = *(const bf16x8*)((const char*)&Alds[b][0] + row * 128 +     \
                                  ((cc ^ (row & 7)) * 16));                  \
      }                                                                      \
      _Pragma("unroll") for (int nf = 0; nf < NF; ++nf) {                    \
        int col = wn * 64 + nf * 16 + (lane & 15);                           \
        int cc = ks * 4 + (lane >> 4);                                       \
        bfr[nf] = *(const bf16x8*)((const char*)&Blds[b][0] + col * 128 +    \
                                   ((cc ^ (col & 7)) * 16));                 \
      }                                                                      \
      _Pragma("unroll") for (int mf = 0; mf < MF; ++mf)                      \
          _Pragma("unroll") for (int nf = 0; nf < NF; ++nf)                  \
              acc[mf][nf] = __builtin_amdgcn_mfma_f32_16x16x32_bf16(         \
                  af[mf], bfr[nf], acc[mf][nf], 0, 0, 0);                    \
    }                                                                        \
  }

  constexpr int NK = KSLICE / 64;  // 16 or 32, always even
  STAGE(0, 0);
  for (int t = 0; t < NK; t += 2) {
    STAGE(1, (t + 1) * 64);
    asm volatile("s_waitcnt vmcnt(5)" ::: "memory");  // tile t landed; t+1 in flight
    __builtin_amdgcn_s_barrier();
    COMPUTE(0);
    __builtin_amdgcn_s_barrier();
    if (t + 2 < NK) {
      STAGE(0, (t + 2) * 64);
      asm volatile("s_waitcnt vmcnt(5)" ::: "memory");
    } else {
      asm volatile("s_waitcnt vmcnt(0)" ::: "memory");
    }
    __builtin_amdgcn_s_barrier();
    COMPUTE(1);
    __builtin_amdgcn_s_barrier();
  }
#undef STAGE
#undef COMPUTE

  // epilogue: C/D layout col=lane&15, row=(lane>>4)*4+reg; bf16 store
  unsigned short* Op = Out + (size_t)ksl * 8192 * ND;
  const int q = lane >> 4, c16 = lane & 15;
#pragma unroll
  for (int mf = 0; mf < MF; ++mf) {
#pragma unroll
    for (int r = 0; r < 4; ++r) {
      int lrow = wm * 32 + mf * 16 + q * 4 + r;
      if (lrow < valid) {
#pragma unroll
        for (int nf = 0; nf < NF; ++nf) {
          int gcol = n0 + wn * 64 + nf * 16 + c16;
          float v = acc[mf][nf][r];
          if (DOSILU) v = v / (1.f + __expf(-v));
          Op[(size_t)(base + m0 + lrow) * ND + gcol] = f2bf(v);
        }
      }
    }
  }
}

// ------- final combine: out[t] = w0*(y0[s0]+y1[s0]) + w1*(y0[s1]+y1[s1]) -------
__global__ __launch_bounds__(256) void moe_combine(
    const unsigned short* __restrict__ y, const int* __restrict__ slot,
    const float* __restrict__ tw, float* __restrict__ out) {
  const int t = blockIdx.x;
  const int s0 = slot[t * 2], s1 = slot[t * 2 + 1];
  const float w0 = tw[t * 2], w1 = tw[t * 2 + 1];
  const int i = threadIdx.x * 4;
  ushort4 a = *(const ushort4*)(y + (size_t)s0 * DDIM + i);
  ushort4 b = *(const ushort4*)(y + (size_t)(8192 + s0) * DDIM + i);
  ushort4 c = *(const ushort4*)(y + (size_t)s1 * DDIM + i);
  ushort4 d = *(const ushort4*)(y + (size_t)(8192 + s1) * DDIM + i);
  float4 r;
  r.x = w0 * (bf2f(a.x) + bf2f(b.x)) + w1 * (bf2f(c.x) + bf2f(d.x));
  r.y = w0 * (bf2f(a.y) + bf2f(b.y)) + w1 * (bf2f(c.y) + bf2f(d.y));
  r.z = w0 * (bf2f(a.z) + bf2f(b.z)) + w1 * (bf2f(c.z) + bf2f(d.z));
  r.w = w0 * (bf2f(a.w) + bf2f(b.w)) + w1 * (bf2f(c.w) + bf2f(d.w));
  *(float4*)(out + (size_t)t * DDIM + i) = r;
}

extern "C" void kernel_launch(void* const* d_in, const int* in_sizes, int n_in,
                              void* d_out, int out_size, void* d_ws, size_t ws_size,
                              hipStream_t stream) {
  const float* x  = (const float*)d_in[0];   // [2,2048,1024]
  const float* Wr = (const float*)d_in[1];   // [8,1024]
  const float* W1 = (const float*)d_in[2];   // [8,1024,4096]
  const float* W2 = (const float*)d_in[3];   // [8,4096,1024]
  float* out = (float*)d_out;                // [2,2048,1024] f32

  char* ws = (char*)d_ws;
  unsigned short* xb = (unsigned short*)ws;                          // 8 MB bf16 tokens
  unsigned short* H  = (unsigned short*)(ws + (size_t)(8 << 20));    // 64 MB bf16 hidden
  unsigned short* WT = (unsigned short*)(ws + (size_t)(72 << 20));   // 64 MB bf16 Wt (shared)
  unsigned short* y  = (unsigned short*)(ws + (size_t)(136 << 20));  // 32 MB bf16 y-pair
  char* meta = ws + (size_t)(168 << 20);
  int* rows   = (int*)meta;                   // 32 KB
  int* te     = (int*)(meta + (32 << 10));    // 32 KB
  float* tw   = (float*)(meta + (64 << 10));  // 32 KB
  int* slot   = (int*)(meta + (96 << 10));    // 32 KB
  int* counts = (int*)(meta + (128 << 10));
  int* offs   = counts + 16;
  int* fill   = counts + 32;
  int* tcnt   = counts + 48;
  int* tlist  = counts + 64;                  // <= 136 entries

  hipMemsetAsync(counts, 0, 256, stream);

  moe_router<<<T_TOK / 4, 256, 0, stream>>>(x, Wr, xb, te, tw);
  moe_count<<<T_TOK / 256, 256, 0, stream>>>(te, counts);
  moe_prefix<<<1, 64, 0, stream>>>(counts, offs, fill, tcnt, tlist);
  moe_scatter<<<T_TOK / 256, 256, 0, stream>>>(te, offs, fill, rows, slot);

  // W1 [E][D=1024][F=4096] -> WT [E][F][D]
  wconv_t<<<dim3(FDIM / 64, DDIM / 64, NEXP), 256, 0, stream>>>(W1, WT, DDIM, FDIM);
  // GEMM1: H[slot] = silu(x[rows[slot]] @ W1[e]); no split
  moe_gemm<DDIM, DDIM, FDIM, true, true>
      <<<TLMAX * (FDIM / 256), 512, 0, stream>>>(xb, WT, rows, offs, tcnt, tlist, H);

  // W2 [E][F=4096][D=1024] -> WT [E][D][F]
  wconv_t<<<dim3(DDIM / 64, FDIM / 64, NEXP), 256, 0, stream>>>(W2, WT, FDIM, DDIM);
  // GEMM2: split-K=2 -> bf16 partial pair y[2][8192][1024]
  moe_gemm<FDIM, FDIM / 2, DDIM, false, false>
      <<<TLMAX * (DDIM / 256) * 2, 512, 0, stream>>>(H, WT, nullptr, offs, tcnt, tlist, y);

  moe_combine<<<T_TOK, 256, 0, stream>>>(y, slot, tw, out);
}

// Round 16
// 306.905 us; speedup vs baseline: 1.2010x; 1.0138x over previous
//
#include <hip/hip_runtime.h>
#include <hip/hip_bf16.h>

#define T_TOK 4096
#define DDIM  1024
#define FDIM  4096
#define NEXP  8
#define TLMAX 136  // max 64-row tiles: 8192/64 + 8 partials

typedef __attribute__((ext_vector_type(8))) short bf16x8;
typedef __attribute__((ext_vector_type(4))) float f32x4;

__device__ __forceinline__ void gl2lds16(const void* g, void* l) {
  __builtin_amdgcn_global_load_lds((const __attribute__((address_space(1))) void*)g,
                                   (__attribute__((address_space(3))) void*)l,
                                   16, 0, 0);
}

// f32 -> bf16 round-to-nearest-even (inputs finite)
__device__ __forceinline__ unsigned short f2bf(float f) {
  unsigned u = __float_as_uint(f);
  unsigned r = (u + 0x7fffu + ((u >> 16) & 1u)) >> 16;
  return (unsigned short)r;
}
__device__ __forceinline__ float bf2f(unsigned short u) {
  return __uint_as_float((unsigned)u << 16);
}

// ---- fused: router (blocks 0..1023) + W1 convert/transpose (blocks 1024..9215) ----
// W1: f32 [E][D][F] -> WT1 bf16 [E][F][D].  Independent work, overlapped in one
// dispatch (router is tiny; wconv is BW-bound).
__global__ __launch_bounds__(256) void moe_router_wc1(
    const float* __restrict__ x, const float* __restrict__ Wr,
    const float* __restrict__ W1, unsigned short* __restrict__ WT1,
    unsigned short* __restrict__ xb, int* __restrict__ te, float* __restrict__ tw) {
  __shared__ float wr[NEXP * DDIM];  // 32 KB (router) / aliased by wconv tile
  const int bid = blockIdx.x;
  const int tid = threadIdx.x;

  if (bid >= T_TOK / 4) {
    // ---- wconv W1 tile: K=DDIM, N=FDIM ----
    const int tau = bid - T_TOK / 4;           // 0..8191
    const int bx = tau & 63;                   // n-tile (FDIM/64)
    const int by = (tau >> 6) & 15;            // k-tile (DDIM/64)
    const int e = tau >> 10;
    unsigned short(*t)[65] = (unsigned short(*)[65])wr;
    const float* src = W1 + (size_t)e * DDIM * FDIM + (size_t)(by * 64) * FDIM + bx * 64;
    unsigned short* dst = WT1 + (size_t)e * FDIM * DDIM + (size_t)(bx * 64) * DDIM + by * 64;
    const int rr = tid >> 4, cc4 = (tid & 15) * 4;
#pragma unroll
    for (int i = 0; i < 4; ++i) {
      int r = i * 16 + rr;
      float4 v = *(const float4*)(src + (size_t)r * FDIM + cc4);
      t[cc4 + 0][r] = f2bf(v.x);
      t[cc4 + 1][r] = f2bf(v.y);
      t[cc4 + 2][r] = f2bf(v.z);
      t[cc4 + 3][r] = f2bf(v.w);
    }
    __syncthreads();
    const int k8 = (tid & 7) * 8;
#pragma unroll
    for (int i = 0; i < 2; ++i) {
      int c = i * 32 + (tid >> 3);
      uint4 pk;
      pk.x = (unsigned)t[c][k8 + 0] | ((unsigned)t[c][k8 + 1] << 16);
      pk.y = (unsigned)t[c][k8 + 2] | ((unsigned)t[c][k8 + 3] << 16);
      pk.z = (unsigned)t[c][k8 + 4] | ((unsigned)t[c][k8 + 5] << 16);
      pk.w = (unsigned)t[c][k8 + 6] | ((unsigned)t[c][k8 + 7] << 16);
      *(uint4*)(dst + (size_t)c * DDIM + k8) = pk;
    }
    return;
  }

  // ---- router ----
#pragma unroll
  for (int i = 0; i < NEXP * DDIM / 256; ++i) wr[i * 256 + tid] = Wr[i * 256 + tid];
  __syncthreads();

  const int wave = tid >> 6, lane = tid & 63;
  const int t = bid * 4 + wave;
  const float* xr = x + (size_t)t * DDIM;
  const int d0 = lane * 16;

  float4 xv[4];
#pragma unroll
  for (int j = 0; j < 4; ++j) xv[j] = *(const float4*)(xr + d0 + j * 4);

  float lg[NEXP];
#pragma unroll
  for (int e = 0; e < NEXP; ++e) {
    float s = 0.f;
#pragma unroll
    for (int j = 0; j < 4; ++j) {
      float4 wv = *(const float4*)(&wr[e * DDIM + d0 + j * 4]);
      s += xv[j].x * wv.x + xv[j].y * wv.y + xv[j].z * wv.z + xv[j].w * wv.w;
    }
    lg[e] = s;
  }
#pragma unroll
  for (int e = 0; e < NEXP; ++e) {
#pragma unroll
    for (int off = 32; off > 0; off >>= 1) lg[e] += __shfl_xor(lg[e], off);
  }

#pragma unroll
  for (int j = 0; j < 4; ++j) {
    ushort4 o;
    o.x = f2bf(xv[j].x); o.y = f2bf(xv[j].y); o.z = f2bf(xv[j].z); o.w = f2bf(xv[j].w);
    *(ushort4*)(xb + (size_t)t * DDIM + d0 + j * 4) = o;
  }

  if (lane == 0) {
    int i0 = 0;
#pragma unroll
    for (int e = 1; e < NEXP; ++e) if (lg[e] > lg[i0]) i0 = e;
    int i1 = (i0 == 0) ? 1 : 0;
#pragma unroll
    for (int e = 0; e < NEXP; ++e) if (e != i0 && lg[e] > lg[i1]) i1 = e;
    float w0 = 1.f / (1.f + __expf(lg[i1] - lg[i0]));
    te[t * 2 + 0] = i0; te[t * 2 + 1] = i1;
    tw[t * 2 + 0] = w0; tw[t * 2 + 1] = 1.f - w0;
  }
}

// -------- expert counts via LDS histogram (128 global atomics total) --------
__global__ __launch_bounds__(256) void moe_count(const int* __restrict__ te,
                                                 int* __restrict__ counts) {
  __shared__ int lh[NEXP];
  const int tid = threadIdx.x;
  if (tid < NEXP) lh[tid] = 0;
  __syncthreads();
  const int t = blockIdx.x * 256 + tid;
  atomicAdd(&lh[te[t * 2 + 0]], 1);
  atomicAdd(&lh[te[t * 2 + 1]], 1);
  __syncthreads();
  if (tid < NEXP) atomicAdd(&counts[tid], lh[tid]);
}

// -------- prefix over experts + build balanced 64-row tile list --------
__global__ void moe_prefix(const int* __restrict__ counts, int* __restrict__ offs,
                           int* __restrict__ fill, int* __restrict__ tcnt,
                           int* __restrict__ tlist) {
  if (threadIdx.x == 0) {
    int s = 0, tt = 0;
    for (int e = 0; e < NEXP; ++e) {
      offs[e] = s;
      int c = counts[e];
      s += c;
      fill[e] = 0;
      for (int mt = 0; mt * 64 < c; ++mt) tlist[tt++] = (e << 8) | mt;
    }
    offs[NEXP] = s;
    tcnt[0] = tt;
  }
}

// -------- scatter with LDS-aggregated ranks (128 contended global atomics) --------
__global__ __launch_bounds__(256) void moe_scatter(
    const int* __restrict__ te, const int* __restrict__ offs, int* __restrict__ fill,
    int* __restrict__ rows, int* __restrict__ slot) {
  __shared__ int lcnt[NEXP], lbase[NEXP];
  const int tid = threadIdx.x;
  if (tid < NEXP) lcnt[tid] = 0;
  __syncthreads();
  const int t = blockIdx.x * 256 + tid;
  const int e0 = te[t * 2 + 0], e1 = te[t * 2 + 1];
  const int r0 = atomicAdd(&lcnt[e0], 1);
  const int r1 = atomicAdd(&lcnt[e1], 1);
  __syncthreads();
  if (tid < NEXP) lbase[tid] = atomicAdd(&fill[tid], lcnt[tid]);
  __syncthreads();
  int p0 = offs[e0] + lbase[e0] + r0;
  int p1 = offs[e1] + lbase[e1] + r1;
  rows[p0] = t; rows[p1] = t;
  slot[t * 2 + 0] = p0; slot[t * 2 + 1] = p1;
}

// ---- fused: GEMM1 (blocks 0..2175, R15-verbatim body) + W2 convert (2176..6271) ----
// W2 conversion (K=FDIM, N=DDIM; 2 tiles per 512-thr block) is independent of GEMM1;
// its BW-bound blocks backfill GEMM1's tail round. WT1 (read) and WT2 (write) are
// separate buffers.
__global__ __launch_bounds__(512, 4) void moe_gemm1_wc2(
    const unsigned short* __restrict__ Asrc, const unsigned short* __restrict__ Wt1,
    const float* __restrict__ W2, unsigned short* __restrict__ WT2,
    const int* __restrict__ rows, const int* __restrict__ offs,
    const int* __restrict__ tcnt, const int* __restrict__ tlist,
    unsigned short* __restrict__ Hout) {
  constexpr int KD = DDIM, ND = FDIM, BM = 64, BN = 256;
  constexpr int NTN = ND / BN;             // 16
  constexpr int NB = TLMAX * NTN;          // 2176, multiple of 8
  constexpr int CB = BN / 64, MF = BM / 32, NF = 4;

  __shared__ alignas(16) unsigned short Alds[2][BM * 64];  // 2 x 8 KB
  __shared__ alignas(16) unsigned short Blds[2][BN * 64];  // 2 x 32 KB (aliased by wconv)

  const int bid = blockIdx.x;
  const int tid = threadIdx.x;

  if (bid >= NB) {
    // ---- wconv W2: K=FDIM, N=DDIM; 2 tiles per block ----
    const int wid = bid - NB;                // 0..4095
    const int sub = tid >> 8, t2 = tid & 255;
    const int tau = wid * 2 + sub;           // 0..8191
    const int bx = tau & 15;                 // n-tile (DDIM/64)
    const int by = (tau >> 4) & 63;          // k-tile (FDIM/64)
    const int e = tau >> 10;
    unsigned short(*t)[65] = (unsigned short(*)[65])((char*)&Blds[0][0] + sub * 8320);
    const float* src = W2 + (size_t)e * FDIM * DDIM + (size_t)(by * 64) * DDIM + bx * 64;
    unsigned short* dst = WT2 + (size_t)e * DDIM * FDIM + (size_t)(bx * 64) * FDIM + by * 64;
    const int rr = t2 >> 4, cc4 = (t2 & 15) * 4;
#pragma unroll
    for (int i = 0; i < 4; ++i) {
      int r = i * 16 + rr;
      float4 v = *(const float4*)(src + (size_t)r * DDIM + cc4);
      t[cc4 + 0][r] = f2bf(v.x);
      t[cc4 + 1][r] = f2bf(v.y);
      t[cc4 + 2][r] = f2bf(v.z);
      t[cc4 + 3][r] = f2bf(v.w);
    }
    __syncthreads();
    const int k8 = (t2 & 7) * 8;
#pragma unroll
    for (int i = 0; i < 2; ++i) {
      int c = i * 32 + (t2 >> 3);
      uint4 pk;
      pk.x = (unsigned)t[c][k8 + 0] | ((unsigned)t[c][k8 + 1] << 16);
      pk.y = (unsigned)t[c][k8 + 2] | ((unsigned)t[c][k8 + 3] << 16);
      pk.z = (unsigned)t[c][k8 + 4] | ((unsigned)t[c][k8 + 5] << 16);
      pk.w = (unsigned)t[c][k8 + 6] | ((unsigned)t[c][k8 + 7] << 16);
      *(uint4*)(dst + (size_t)c * FDIM + k8) = pk;
    }
    return;
  }

  // ---- GEMM1 body (R15 template, S=1/ksl=0/GATHER/DOSILU folded) ----
  const int orig = (bid & 7) * (NB >> 3) + (bid >> 3);
  const int TT = tcnt[0];
  if (orig >= TT * NTN) return;
  const int tt = orig % TT;
  const int nt = orig / TT;
  const int pk = tlist[tt];
  const int e = pk >> 8, mt = pk & 255;

  const int base = offs[e];
  const int cnt = offs[e + 1] - base;
  const int m0 = mt * BM;
  const int valid = min(BM, cnt - m0);

  const int w = tid >> 6, lane = tid & 63;
  const int wm = w >> 2, wn = w & 3;

  const int n0 = nt * BN;
  const unsigned short* Wb = Wt1 + (size_t)e * ND * KD + (size_t)n0 * KD;

  const int cc8 = ((lane & 7) ^ (lane >> 3)) * 8;
  const int ar = w * 8 + (lane >> 3);
  const int aslot = base + m0 + min(ar, valid - 1);
  const size_t aoff = (size_t)rows[aslot] * KD + cc8;
  size_t boff[CB];
#pragma unroll
  for (int s = 0; s < CB; ++s) {
    int r = s * 64 + w * 8 + (lane >> 3);
    boff[s] = (size_t)r * KD + cc8;
  }

  f32x4 acc[MF][NF] = {};

#define STAGE(b, k0)                                                         \
  {                                                                          \
    gl2lds16(Asrc + aoff + (k0), &Alds[b][w * 512]);                         \
    _Pragma("unroll") for (int s = 0; s < CB; ++s)                           \
        gl2lds16(Wb + boff[s] + (k0), &Blds[b][(s * 512 + w * 64) * 8]);     \
  }

#define COMPUTE(b)                                                           \
  {                                                                          \
    _Pragma("unroll") for (int ks = 0; ks < 2; ++ks) {                       \
      bf16x8 af[MF], bfr[NF];                                                \
      _Pragma("unroll") for (int mf = 0; mf < MF; ++mf) {                    \
        int row = wm * 32 + mf * 16 + (lane & 15);                           \
        int cc = ks * 4 + (lane >> 4);                                       \
        af[mf] = *(const bf16x8*)((const char*)&Alds[b][0] + row * 128 +     \
                                  ((cc ^ (row & 7)) * 16));                  \
      }                                                                      \
      _Pragma("unroll") for (int nf = 0; nf < NF; ++nf) {                    \
        int col = wn * 64 + nf * 16 + (lane & 15);                           \
        int cc = ks * 4 + (lane >> 4);                                       \
        bfr[nf] = *(const bf16x8*)((const char*)&Blds[b][0] + col * 128 +    \
                                   ((cc ^ (col & 7)) * 16));                 \
      }                                                                      \
      _Pragma("unroll") for (int mf = 0; mf < MF; ++mf)                      \
          _Pragma("unroll") for (int nf = 0; nf < NF; ++nf)                  \
              acc[mf][nf] = __builtin_amdgcn_mfma_f32_16x16x32_bf16(         \
                  af[mf], bfr[nf], acc[mf][nf], 0, 0, 0);                    \
    }                                                                        \
  }

  constexpr int NK = KD / 64;  // 16
  STAGE(0, 0);
  for (int t = 0; t < NK; t += 2) {
    STAGE(1, (t + 1) * 64);
    asm volatile("s_waitcnt vmcnt(5)" ::: "memory");
    __builtin_amdgcn_s_barrier();
    COMPUTE(0);
    __builtin_amdgcn_s_barrier();
    if (t + 2 < NK) {
      STAGE(0, (t + 2) * 64);
      asm volatile("s_waitcnt vmcnt(5)" ::: "memory");
    } else {
      asm volatile("s_waitcnt vmcnt(0)" ::: "memory");
    }
    __builtin_amdgcn_s_barrier();
    COMPUTE(1);
    __builtin_amdgcn_s_barrier();
  }
#undef STAGE
#undef COMPUTE

  const int q = lane >> 4, c16 = lane & 15;
#pragma unroll
  for (int mf = 0; mf < MF; ++mf) {
#pragma unroll
    for (int r = 0; r < 4; ++r) {
      int lrow = wm * 32 + mf * 16 + q * 4 + r;
      if (lrow < valid) {
#pragma unroll
        for (int nf = 0; nf < NF; ++nf) {
          int gcol = n0 + wn * 64 + nf * 16 + c16;
          float v = acc[mf][nf][r];
          v = v / (1.f + __expf(-v));
          Hout[(size_t)(base + m0 + lrow) * ND + gcol] = f2bf(v);
        }
      }
    }
  }
}

// ------- grouped GEMM (R15 verbatim): 64x256 tile, BK=64, 2-phase counted dbuf ----
template <int KD, int KSLICE, int ND, bool GATHER, bool DOSILU>
__global__ __launch_bounds__(512, 4) void moe_gemm(
    const unsigned short* __restrict__ Asrc, const unsigned short* __restrict__ Wt,
    const int* __restrict__ rows, const int* __restrict__ offs,
    const int* __restrict__ tcnt, const int* __restrict__ tlist,
    unsigned short* __restrict__ Out) {
  constexpr int BM = 64, BN = 256;
  constexpr int S = KD / KSLICE;
  constexpr int NTN = ND / BN;
  constexpr int NPAN = NTN * S;
  constexpr int NB = TLMAX * NPAN;
  constexpr int CB = BN / 64;
  constexpr int MF = BM / 32, NF = 4;

  __shared__ alignas(16) unsigned short Alds[2][BM * 64];
  __shared__ alignas(16) unsigned short Blds[2][BN * 64];

  const int bid = blockIdx.x;
  const int orig = (bid & 7) * (NB >> 3) + (bid >> 3);
  const int TT = tcnt[0];
  if (orig >= TT * NPAN) return;
  const int tt = orig % TT;
  const int panel = orig / TT;
  const int nt = panel % NTN;
  const int ksl = panel / NTN;
  const int pk = tlist[tt];
  const int e = pk >> 8, mt = pk & 255;

  const int base = offs[e];
  const int cnt = offs[e + 1] - base;
  const int m0 = mt * BM;
  const int valid = min(BM, cnt - m0);
  const size_t koff = (size_t)ksl * KSLICE;

  const int tid = threadIdx.x;
  const int w = tid >> 6, lane = tid & 63;
  const int wm = w >> 2, wn = w & 3;

  const int n0 = nt * BN;
  const unsigned short* Wb = Wt + (size_t)e * ND * KD + (size_t)n0 * KD + koff;

  const int cc8 = ((lane & 7) ^ (lane >> 3)) * 8;
  const int ar = w * 8 + (lane >> 3);
  const int aslot = base + m0 + min(ar, valid - 1);
  const size_t aoff = (size_t)(GATHER ? rows[aslot] : aslot) * KD + koff + cc8;
  size_t boff[CB];
#pragma unroll
  for (int s = 0; s < CB; ++s) {
    int r = s * 64 + w * 8 + (lane >> 3);
    boff[s] = (size_t)r * KD + cc8;
  }

  f32x4 acc[MF][NF] = {};

#define STAGE(b, k0)                                                         \
  {                                                                          \
    gl2lds16(Asrc + aoff + (k0), &Alds[b][w * 512]);                         \
    _Pragma("unroll") for (int s = 0; s < CB; ++s)                           \
        gl2lds16(Wb + boff[s] + (k0), &Blds[b][(s * 512 + w * 64) * 8]);     \
  }

#define COMPUTE(b)                                                           \
  {                                                                          \
    _Pragma("unroll") for (int ks = 0; ks < 2; ++ks) {                       \
      bf16x8 af[MF], bfr[NF];                                                \
      _Pragma("unroll") for (int mf = 0; mf < MF; ++mf) {                    \
        int row = wm * 32 + mf * 16 + (lane & 15);                           \
        int cc = ks * 4 + (lane >> 4);                                       \
        af[mf] = *(const bf16x8*)((const char*)&Alds[b][0] + row * 128 +     \
                                  ((cc ^ (row & 7)) * 16));                  \
      }                                                                      \
      _Pragma("unroll") for (int nf = 0; nf < NF; ++nf) {                    \
        int col = wn * 64 + nf * 16 + (lane & 15);                           \
        int cc = ks * 4 + (lane >> 4);                                       \
        bfr[nf] = *(const bf16x8*)((const char*)&Blds[b][0] + col * 128 +    \
                                   ((cc ^ (col & 7)) * 16));                 \
      }                                                                      \
      _Pragma("unroll") for (int mf = 0; mf < MF; ++mf)                      \
          _Pragma("unroll") for (int nf = 0; nf < NF; ++nf)                  \
              acc[mf][nf] = __builtin_amdgcn_mfma_f32_16x16x32_bf16(         \
                  af[mf], bfr[nf], acc[mf][nf], 0, 0, 0);                    \
    }                                                                        \
  }

  constexpr int NK = KSLICE / 64;
  STAGE(0, 0);
  for (int t = 0; t < NK; t += 2) {
    STAGE(1, (t + 1) * 64);
    asm volatile("s_waitcnt vmcnt(5)" ::: "memory");
    __builtin_amdgcn_s_barrier();
    COMPUTE(0);
    __builtin_amdgcn_s_barrier();
    if (t + 2 < NK) {
      STAGE(0, (t + 2) * 64);
      asm volatile("s_waitcnt vmcnt(5)" ::: "memory");
    } else {
      asm volatile("s_waitcnt vmcnt(0)" ::: "memory");
    }
    __builtin_amdgcn_s_barrier();
    COMPUTE(1);
    __builtin_amdgcn_s_barrier();
  }
#undef STAGE
#undef COMPUTE

  unsigned short* Op = Out + (size_t)ksl * 8192 * ND;
  const int q = lane >> 4, c16 = lane & 15;
#pragma unroll
  for (int mf = 0; mf < MF; ++mf) {
#pragma unroll
    for (int r = 0; r < 4; ++r) {
      int lrow = wm * 32 + mf * 16 + q * 4 + r;
      if (lrow < valid) {
#pragma unroll
        for (int nf = 0; nf < NF; ++nf) {
          int gcol = n0 + wn * 64 + nf * 16 + c16;
          float v = acc[mf][nf][r];
          if (DOSILU) v = v / (1.f + __expf(-v));
          Op[(size_t)(base + m0 + lrow) * ND + gcol] = f2bf(v);
        }
      }
    }
  }
}

// ------- final combine: out[t] = w0*(y0[s0]+y1[s0]) + w1*(y0[s1]+y1[s1]) -------
__global__ __launch_bounds__(256) void moe_combine(
    const unsigned short* __restrict__ y, const int* __restrict__ slot,
    const float* __restrict__ tw, float* __restrict__ out) {
  const int t = blockIdx.x;
  const int s0 = slot[t * 2], s1 = slot[t * 2 + 1];
  const float w0 = tw[t * 2], w1 = tw[t * 2 + 1];
  const int i = threadIdx.x * 4;
  ushort4 a = *(const ushort4*)(y + (size_t)s0 * DDIM + i);
  ushort4 b = *(const ushort4*)(y + (size_t)(8192 + s0) * DDIM + i);
  ushort4 c = *(const ushort4*)(y + (size_t)s1 * DDIM + i);
  ushort4 d = *(const ushort4*)(y + (size_t)(8192 + s1) * DDIM + i);
  float4 r;
  r.x = w0 * (bf2f(a.x) + bf2f(b.x)) + w1 * (bf2f(c.x) + bf2f(d.x));
  r.y = w0 * (bf2f(a.y) + bf2f(b.y)) + w1 * (bf2f(c.y) + bf2f(d.y));
  r.z = w0 * (bf2f(a.z) + bf2f(b.z)) + w1 * (bf2f(c.z) + bf2f(d.z));
  r.w = w0 * (bf2f(a.w) + bf2f(b.w)) + w1 * (bf2f(c.w) + bf2f(d.w));
  *(float4*)(out + (size_t)t * DDIM + i) = r;
}

extern "C" void kernel_launch(void* const* d_in, const int* in_sizes, int n_in,
                              void* d_out, int out_size, void* d_ws, size_t ws_size,
                              hipStream_t stream) {
  const float* x  = (const float*)d_in[0];   // [2,2048,1024]
  const float* Wr = (const float*)d_in[1];   // [8,1024]
  const float* W1 = (const float*)d_in[2];   // [8,1024,4096]
  const float* W2 = (const float*)d_in[3];   // [8,4096,1024]
  float* out = (float*)d_out;                // [2,2048,1024] f32

  char* ws = (char*)d_ws;
  unsigned short* xb  = (unsigned short*)ws;                          // 8 MB bf16 tokens
  unsigned short* H   = (unsigned short*)(ws + (size_t)(8 << 20));    // 64 MB bf16 hidden
  unsigned short* WT1 = (unsigned short*)(ws + (size_t)(72 << 20));   // 64 MB bf16 W1t
  unsigned short* WT2 = (unsigned short*)(ws + (size_t)(136 << 20));  // 64 MB bf16 W2t
  unsigned short* y   = (unsigned short*)(ws + (size_t)(200 << 20));  // 32 MB bf16 y-pair
  char* meta = ws + (size_t)(232 << 20);
  int* rows   = (int*)meta;                   // 32 KB
  int* te     = (int*)(meta + (32 << 10));    // 32 KB
  float* tw   = (float*)(meta + (64 << 10));  // 32 KB
  int* slot   = (int*)(meta + (96 << 10));    // 32 KB
  int* counts = (int*)(meta + (128 << 10));
  int* offs   = counts + 16;
  int* fill   = counts + 32;
  int* tcnt   = counts + 48;
  int* tlist  = counts + 64;                  // <= 136 entries

  hipMemsetAsync(counts, 0, 256, stream);

  // router (1024 blocks) + W1 conversion (8192 blocks), one dispatch
  moe_router_wc1<<<T_TOK / 4 + 8192, 256, 0, stream>>>(x, Wr, W1, WT1, xb, te, tw);
  moe_count<<<T_TOK / 256, 256, 0, stream>>>(te, counts);
  moe_prefix<<<1, 64, 0, stream>>>(counts, offs, fill, tcnt, tlist);
  moe_scatter<<<T_TOK / 256, 256, 0, stream>>>(te, offs, fill, rows, slot);

  // GEMM1 (2176 blocks) + W2 conversion (4096 blocks), one dispatch
  moe_gemm1_wc2<<<TLMAX * (FDIM / 256) + 4096, 512, 0, stream>>>(
      xb, WT1, W2, WT2, rows, offs, tcnt, tlist, H);

  // GEMM2: split-K=2 -> bf16 partial pair y[2][8192][1024]
  moe_gemm<FDIM, FDIM / 2, DDIM, false, false>
      <<<TLMAX * (DDIM / 256) * 2, 512, 0, stream>>>(H, WT2, nullptr, offs, tcnt, tlist, y);

  moe_combine<<<T_TOK, 256, 0, stream>>>(y, slot, tw, out);
}